// Round 2
// baseline (810.945 us; speedup 1.0000x reference)
//
#include <hip/hip_runtime.h>
#include <cstddef>

#define NPIX 65536
#define PI_F 3.14159265358979323846f

__device__ __forceinline__ void cacc(float2& acc, float2 a, float2 b) {
  acc.x = fmaf(a.x, b.x, fmaf(-a.y, b.y, acc.x));
  acc.y = fmaf(a.x, b.y, fmaf(a.y, b.x, acc.y));
}

// ---------------- 256-point radix-2 DIT FFT in LDS (one wave per line) -----
__device__ __forceinline__ void fft256(float* re, float* im, const float* twr,
                                       const float* twi, int lane) {
  #pragma unroll
  for (int s = 0; s < 8; ++s) {
    __syncthreads();
    const int half = 1 << s;
    #pragma unroll
    for (int r = 0; r < 2; ++r) {
      int m  = lane + 64*r;
      int t  = m & (half - 1);
      int g  = m >> s;
      int i0 = (g << (s+1)) + t;
      int i1 = i0 + half;
      int ti = t << (7 - s);
      float wr = twr[ti], wi = twi[ti];
      float br = re[i1], bi = im[i1];
      float vr = br*wr - bi*wi;
      float vi = br*wi + bi*wr;
      float ar = re[i0], ai = im[i0];
      re[i0] = ar + vr; im[i0] = ai + vi;
      re[i1] = ar - vr; im[i1] = ai - vi;
    }
  }
  __syncthreads();
}

// ---------------- setup: A1, A2T, E1, E2 ------------------------------------
__global__ __launch_bounds__(256) void k_setup(const float2* __restrict__ p1,
    const float2* __restrict__ p2, const float* __restrict__ txv,
    const float* __restrict__ tyv, float2* __restrict__ A1,
    float2* __restrict__ A2T, float2* __restrict__ E1, float2* __restrict__ E2) {
  int gid = blockIdx.x*256 + threadIdx.x;          // [0, 524288)
  int o = gid & 255, p = (gid>>8)&7, k = (gid>>11)&15, i = gid>>15;
  float ko = (o < 128) ? (float)o : (float)(o - 256);
  float dty = tyv[1] - tyv[0];
  float dtx = txv[1] - txv[0];
  const float TWO_PI = 6.283185307179586f;
  {
    float lam = TWO_PI * ko / (256.0f * dty);
    float2 pv = p1[(i*16+k)*8 + p];
    float xr = -pv.x, yi = lam - pv.y;
    float D = xr*xr + yi*yi;
    A1[((size_t)((i*16+k)*8 + p))*256 + o] = make_float2(xr/D, -yi/D);
    float tv = tyv[o];
    float m = expf(pv.x*tv);
    E1[((size_t)((i*16+k)*8 + p))*256 + o] = make_float2(m*cosf(pv.y*tv), m*sinf(pv.y*tv));
  }
  {
    float lam = TWO_PI * ko / (256.0f * dtx);
    float2 pv = p2[(i*16+k)*8 + p];
    float xr = -pv.x, yi = lam - pv.y;
    float D = xr*xr + yi*yi;
    A2T[((size_t)i*256 + o)*128 + k*8 + p] = make_float2(xr/D, -yi/D);
    float tv = txv[o];
    float m = expf(pv.x*tv);
    E2[((size_t)((i*16+k)*8 + p))*256 + o] = make_float2(m*cosf(pv.y*tv), m*sinf(pv.y*tv));
  }
}

// ---------------- stats of v (recomputed from x) ----------------------------
__global__ __launch_bounds__(256) void k_stats_v(const float* __restrict__ x,
    const float* __restrict__ fc0w, const float* __restrict__ fc0b,
    float2* __restrict__ stats) {
  int img = blockIdx.x, tid = threadIdx.x;
  int k = img & 15, b = img >> 4;
  float w0 = fc0w[k], w1 = fc0w[16+k], w2 = fc0w[32+k], w3 = fc0w[48+k], w4 = fc0w[64+k];
  float base = fc0b[k] + (tid*(1.0f/255.0f))*w4;
  const float* xb = x + (size_t)b*3*NPIX;
  float s = 0.f, s2 = 0.f;
  for (int it = 0; it < 256; ++it) {
    int p = it*256 + tid;
    float val = base + (it*(1.0f/255.0f))*w3 + xb[p]*w0 + xb[NPIX+p]*w1 + xb[2*NPIX+p]*w2;
    s += val; s2 += val*val;
  }
  __shared__ float rs[256], rq[256];
  rs[tid] = s; rq[tid] = s2;
  __syncthreads();
  for (int off = 128; off > 0; off >>= 1) {
    if (tid < off) { rs[tid] += rs[tid+off]; rq[tid] += rq[tid+off]; }
    __syncthreads();
  }
  if (tid == 0) {
    float mean = rs[0] * (1.0f/65536.0f);
    float var  = rq[0] * (1.0f/65536.0f) - mean*mean;
    stats[img] = make_float2(mean, rsqrtf(var + 1e-5f));
  }
}

// ---------------- stats of a real plane buffer ------------------------------
__global__ __launch_bounds__(256) void k_stats_p(const float* __restrict__ v,
    float2* __restrict__ stats) {
  int img = blockIdx.x, tid = threadIdx.x;
  const float* p = v + (size_t)img*NPIX;
  float s = 0.f, s2 = 0.f;
  for (int it = 0; it < 256; ++it) { float a = p[it*256 + tid]; s += a; s2 += a*a; }
  __shared__ float rs[256], rq[256];
  rs[tid] = s; rq[tid] = s2;
  __syncthreads();
  for (int off = 128; off > 0; off >>= 1) {
    if (tid < off) { rs[tid] += rs[tid+off]; rq[tid] += rq[tid+off]; }
    __syncthreads();
  }
  if (tid == 0) {
    float mean = rs[0] * (1.0f/65536.0f);
    float var  = rq[0] * (1.0f/65536.0f) - mean*mean;
    stats[img] = make_float2(mean, rsqrtf(var + 1e-5f));
  }
}

// ---------------- FFT over rows, input = normalized v recomputed from x -----
__global__ __launch_bounds__(256) void k_fft_v(const float* __restrict__ x,
    const float* __restrict__ fc0w, const float* __restrict__ fc0b,
    const float2* __restrict__ stats, float2* __restrict__ out) {
  __shared__ float sre[4][256], sim[4][256];
  __shared__ float twr[128], twi[128];
  int tid = threadIdx.x, lane = tid & 63, rowi = tid >> 6;
  int bid = blockIdx.x;                  // [0, 8192)
  int img = bid >> 6;
  int h   = (bid & 63)*4 + rowi;
  int k = img & 15, b = img >> 4;
  if (tid < 128) {
    float ang = (PI_F/128.0f)*tid;
    twr[tid] = cosf(ang); twi[tid] = -sinf(ang);
  }
  float2 st = stats[img];
  float w0 = fc0w[k], w1 = fc0w[16+k], w2 = fc0w[32+k], w3 = fc0w[48+k], w4 = fc0w[64+k];
  float bb = fc0b[k] + (h*(1.0f/255.0f))*w3;
  const float* xb = x + (size_t)b*3*NPIX + (size_t)h*256;
  float* re = sre[rowi]; float* im_ = sim[rowi];
  #pragma unroll
  for (int r = 0; r < 4; ++r) {
    int j = lane + 64*r;
    float val = bb + (j*(1.0f/255.0f))*w4 + xb[j]*w0 + xb[NPIX+j]*w1 + xb[2*NPIX+j]*w2;
    val = (val - st.x)*st.y;
    int bj = __brev((unsigned)j) >> 24;
    re[bj] = val; im_[bj] = 0.f;
  }
  fft256(re, im_, twr, twi, lane);
  float2* op = out + ((size_t)img*256 + h)*256;
  #pragma unroll
  for (int r = 0; r < 4; ++r) { int j = lane + 64*r; op[j] = make_float2(re[j], im_[j]); }
}

// ---------------- generic complex row FFT (dir=-1 fwd, +1 inv) --------------
__global__ __launch_bounds__(256) void k_fft_c(const float2* __restrict__ in,
    float2* __restrict__ out, float dir, float scale) {
  __shared__ float sre[4][256], sim[4][256];
  __shared__ float twr[128], twi[128];
  int tid = threadIdx.x, lane = tid & 63, rowi = tid >> 6;
  size_t row = (size_t)blockIdx.x*4 + rowi;      // [0, 32768)
  if (tid < 128) {
    float ang = (PI_F/128.0f)*tid;
    twr[tid] = cosf(ang); twi[tid] = dir*sinf(ang);
  }
  const float2* ip = in + row*256;
  float* re = sre[rowi]; float* im_ = sim[rowi];
  #pragma unroll
  for (int r = 0; r < 4; ++r) {
    int j = lane + 64*r;
    float2 v = ip[j];
    int bj = __brev((unsigned)j) >> 24;
    re[bj] = v.x; im_[bj] = v.y;
  }
  fft256(re, im_, twr, twi, lane);
  float2* op = out + row*256;
  #pragma unroll
  for (int r = 0; r < 4; ++r) { int j = lane + 64*r; op[j] = make_float2(re[j]*scale, im_[j]*scale); }
}

// ---------------- inverse row FFT, write real part only ---------------------
__global__ __launch_bounds__(256) void k_ifft_real(const float2* __restrict__ in,
    float* __restrict__ out, float scale) {
  __shared__ float sre[4][256], sim[4][256];
  __shared__ float twr[128], twi[128];
  int tid = threadIdx.x, lane = tid & 63, rowi = tid >> 6;
  size_t row = (size_t)blockIdx.x*4 + rowi;
  if (tid < 128) {
    float ang = (PI_F/128.0f)*tid;
    twr[tid] = cosf(ang); twi[tid] = sinf(ang);
  }
  const float2* ip = in + row*256;
  float* re = sre[rowi]; float* im_ = sim[rowi];
  #pragma unroll
  for (int r = 0; r < 4; ++r) {
    int j = lane + 64*r;
    float2 v = ip[j];
    int bj = __brev((unsigned)j) >> 24;
    re[bj] = v.x; im_[bj] = v.y;
  }
  fft256(re, im_, twr, twi, lane);
  float* op = out + row*256;
  #pragma unroll
  for (int r = 0; r < 4; ++r) { int j = lane + 64*r; op[j] = re[j]*scale; }
}

// ---------------- per-image complex transpose -------------------------------
__global__ __launch_bounds__(256) void k_trans_c(const float2* __restrict__ in,
    float2* __restrict__ out) {
  __shared__ float2 tile[32][33];
  int img = blockIdx.y;
  int tx = blockIdx.x & 7, tyb = blockIdx.x >> 3;
  int lx = threadIdx.x & 31, ly = threadIdx.x >> 5;     // 32 x 8
  const float2* ip = in + (size_t)img*NPIX;
  float2* op = out + (size_t)img*NPIX;
  #pragma unroll
  for (int r = 0; r < 4; ++r)
    tile[ly + r*8][lx] = ip[(size_t)(tyb*32 + ly + r*8)*256 + tx*32 + lx];
  __syncthreads();
  #pragma unroll
  for (int r = 0; r < 4; ++r)
    op[(size_t)(tx*32 + ly + r*8)*256 + tyb*32 + lx] = tile[lx][ly + r*8];
}

// ---------------- per-image real transpose ----------------------------------
__global__ __launch_bounds__(256) void k_trans_r(const float* __restrict__ in,
    float* __restrict__ out) {
  __shared__ float tile[32][33];
  int img = blockIdx.y;
  int tx = blockIdx.x & 7, tyb = blockIdx.x >> 3;
  int lx = threadIdx.x & 31, ly = threadIdx.x >> 5;
  const float* ip = in + (size_t)img*NPIX;
  float* op = out + (size_t)img*NPIX;
  #pragma unroll
  for (int r = 0; r < 4; ++r)
    tile[ly + r*8][lx] = ip[(size_t)(tyb*32 + ly + r*8)*256 + tx*32 + lx];
  __syncthreads();
  #pragma unroll
  for (int r = 0; r < 4; ++r)
    op[(size_t)(tx*32 + ly + r*8)*256 + tyb*32 + lx] = tile[lx][ly + r*8];
}

// ---- G quarter: for i in [pass*4, pass*4+4): G[iq,k,o,x] -------------------
__global__ __launch_bounds__(256) void k_Gq(const float2* __restrict__ res,
    const float2* __restrict__ A1, const float2* __restrict__ A2T,
    float2* __restrict__ G, int pass) {
  int bid = blockIdx.x;               // ikl*8 + ob, ikl in [0,64)
  int ob = bid & 7, ikl = bid >> 3;
  int iq = ikl >> 4, k = ikl & 15;
  int i = pass*4 + iq;
  int ik = i*16 + k;
  int tid = threadIdx.x;
  __shared__ float2 rbuf[64];         // [p][q]
  __shared__ float2 a1[8][32];
  __shared__ float2 T[8][33];         // [q][ol], padded
  if (tid < 64) rbuf[tid] = res[(size_t)ik*64 + tid];
  { int p = tid >> 5, ol = tid & 31; a1[p][ol] = A1[((size_t)ik*8 + p)*256 + ob*32 + ol]; }
  __syncthreads();
  {
    int q = tid >> 5, ol = tid & 31;
    float2 acc = make_float2(0.f, 0.f);
    #pragma unroll
    for (int p = 0; p < 8; ++p) cacc(acc, rbuf[p*8+q], a1[p][ol]);
    T[q][ol] = acc;
  }
  __syncthreads();
  int x = tid;
  float2 a2[8];
  #pragma unroll
  for (int q = 0; q < 8; ++q) a2[q] = A2T[((size_t)i*256 + x)*128 + k*8 + q];
  for (int ol = 0; ol < 32; ++ol) {
    float2 acc = make_float2(0.f, 0.f);
    #pragma unroll
    for (int q = 0; q < 8; ++q) cacc(acc, T[q][ol], a2[q]);
    G[((size_t)(iq*16+k)*256 + ob*32 + ol)*256 + x] = acc;
  }
}

// ---------------- S[n,i,o,(k,q)] = sum_x alpha[n,i,o,x] A2[i,k,q,x] ---------
__global__ __launch_bounds__(256) void k_S(const float2* __restrict__ alpha,
    const float2* __restrict__ A2T, float2* __restrict__ S) {
  __shared__ float2 al[16][256];
  int bid = blockIdx.x;               // (n*16+i)*16 + oblk
  int oblk = bid & 15, ni = bid >> 4;
  int i = ni & 15;
  int tid = threadIdx.x;
  const float2* ap = alpha + ((size_t)ni*256 + oblk*16)*256;
  for (int r = 0; r < 16; ++r) al[r][tid] = ap[(size_t)r*256 + tid];
  __syncthreads();
  int j = tid & 127, oh = tid >> 7;
  float2 acc[8];
  #pragma unroll
  for (int ol = 0; ol < 8; ++ol) acc[ol] = make_float2(0.f, 0.f);
  for (int xx = 0; xx < 256; ++xx) {
    float2 a2 = A2T[((size_t)i*256 + xx)*128 + j];
    #pragma unroll
    for (int ol = 0; ol < 8; ++ol) cacc(acc[ol], al[oh*8+ol][xx], a2);
  }
  #pragma unroll
  for (int ol = 0; ol < 8; ++ol) {
    int o = oblk*16 + oh*8 + ol;
    S[((size_t)ni*256 + o)*128 + j] = acc[ol];
  }
}

// ---------------- Mt[n,i,k,p,q] = sum_o S[n,i,o,(k,q)] A1[i,k,p,o] ----------
__global__ __launch_bounds__(64) void k_Mt(const float2* __restrict__ S,
    const float2* __restrict__ A1, float2* __restrict__ Mt) {
  __shared__ float2 sl[8][258];
  __shared__ float2 a1l[8][258];
  int bid = blockIdx.x;               // (n*16+i)*16 + k
  int k = bid & 15, ni = bid >> 4;
  int i = ni & 15;
  int ik = i*16 + k;
  int tid = threadIdx.x;
  for (int e = 0; e < 32; ++e) {
    int lin = tid + 64*e;             // 0..2047
    int o = lin >> 3, q = lin & 7;
    sl[q][o] = S[((size_t)ni*256 + o)*128 + k*8 + q];
  }
  for (int e = 0; e < 32; ++e) {
    int lin = tid + 64*e;
    int p = lin >> 8, o = lin & 255;
    a1l[p][o] = A1[((size_t)ik*8 + p)*256 + o];
  }
  __syncthreads();
  int p = tid >> 3, q = tid & 7;
  float2 acc = make_float2(0.f, 0.f);
  for (int o = 0; o < 256; ++o) cacc(acc, sl[q][o], a1l[p][o]);
  Mt[(size_t)bid*64 + p*8 + q] = acc;
}

// ---------------- out2[n,k,p,q] = sum_i Mt[n,i,k,p,q] res[i,k,p,q] ----------
__global__ __launch_bounds__(256) void k_out2(const float2* __restrict__ Mt,
    const float2* __restrict__ res, float2* __restrict__ out2) {
  int gid = blockIdx.x*256 + threadIdx.x;   // [0, 8192)
  int pq = gid & 63, k = (gid >> 6) & 15, n = gid >> 10;
  float2 acc = make_float2(0.f, 0.f);
  for (int i = 0; i < 16; ++i)
    cacc(acc, Mt[((size_t)((n*16+i)*16 + k))*64 + pq], res[((size_t)(i*16+k))*64 + pq]);
  out2[((size_t)(n*16+k))*64 + pq] = acc;
}

// ---- out1 accumulate over one i-quarter ------------------------------------
__global__ __launch_bounds__(256) void k_out1_acc(const float2* __restrict__ alpha,
    const float2* __restrict__ G, float2* __restrict__ out1, int pass) {
  int bid = blockIdx.x;               // o*4 + bp
  int bp = bid & 3, o = bid >> 2;
  int x = threadIdx.x;
  float2 al0[4], al1[4];
  #pragma unroll
  for (int ii = 0; ii < 4; ++ii) {
    int i = pass*4 + ii;
    al0[ii] = alpha[(((size_t)((bp*2+0)*16 + i))*256 + o)*256 + x];
    al1[ii] = alpha[(((size_t)((bp*2+1)*16 + i))*256 + o)*256 + x];
  }
  for (int k = 0; k < 16; ++k) {
    size_t o0i = (((size_t)((bp*2+0)*16 + k))*256 + o)*256 + x;
    size_t o1i = (((size_t)((bp*2+1)*16 + k))*256 + o)*256 + x;
    float2 a0, a1v;
    if (pass == 0) { a0 = make_float2(0.f,0.f); a1v = make_float2(0.f,0.f); }
    else           { a0 = out1[o0i];            a1v = out1[o1i]; }
    #pragma unroll
    for (int ii = 0; ii < 4; ++ii) {
      float2 g = G[(((size_t)(ii*16 + k))*256 + o)*256 + x];
      cacc(a0,  al0[ii], g);
      cacc(a1v, al1[ii], g);
    }
    out1[o0i] = a0;
    out1[o1i] = a1v;
  }
}

// ---------------- U[n,j,kk,q,z] = sum_p out2[n,j,p,q] E1[j,kk,p,z] ----------
__global__ __launch_bounds__(256) void k_U(const float2* __restrict__ out2,
    const float2* __restrict__ E1, float2* __restrict__ U) {
  int bid = blockIdx.x;               // (n*16+j)*16 + kk
  int kk = bid & 15, nj = bid >> 4;
  int j = nj & 15;
  int z = threadIdx.x;
  __shared__ float2 o2[64];
  if (threadIdx.x < 64) o2[threadIdx.x] = out2[(size_t)nj*64 + threadIdx.x];
  __syncthreads();
  float2 e1[8];
  #pragma unroll
  for (int p = 0; p < 8; ++p) e1[p] = E1[(((size_t)(j*16+kk))*8 + p)*256 + z];
  #pragma unroll
  for (int q = 0; q < 8; ++q) {
    float2 acc = make_float2(0.f, 0.f);
    #pragma unroll
    for (int p = 0; p < 8; ++p) cacc(acc, o2[p*8+q], e1[p]);
    U[(((size_t)bid)*8 + q)*256 + z] = acc;
  }
}

// ---------------- x1pre += Re(sum_{j,q} U E2)/65536 -------------------------
__global__ __launch_bounds__(256) void k_x2t(const float2* __restrict__ U,
    const float2* __restrict__ E2, float* __restrict__ x1pre) {
  int bid = blockIdx.x;               // (n*16+kk)*32 + zb
  int zb = bid & 31, nk = bid >> 5;
  int kk = nk & 15, n = nk >> 4;
  int x = threadIdx.x;
  __shared__ float2 ul[1024];         // [j][q][z8]
  for (int e = 0; e < 4; ++e) {
    int lin = threadIdx.x + 256*e;
    int zz = lin & 7, q = (lin >> 3) & 7, j = lin >> 6;
    ul[lin] = U[((((size_t)(n*16+j))*16 + kk)*8 + q)*256 + zb*8 + zz];
  }
  __syncthreads();
  float acc[8] = {0.f,0.f,0.f,0.f,0.f,0.f,0.f,0.f};
  for (int j = 0; j < 16; ++j) {
    #pragma unroll
    for (int q = 0; q < 8; ++q) {
      float2 e2 = E2[(((size_t)(j*16+kk))*8 + q)*256 + x];
      const float2* up = &ul[(j*8+q)*8];
      #pragma unroll
      for (int zz = 0; zz < 8; ++zz) {
        float2 u = up[zz];
        acc[zz] = fmaf(u.x, e2.x, fmaf(-u.y, e2.y, acc[zz]));
      }
    }
  }
  const float sc = 1.0f/65536.0f;
  #pragma unroll
  for (int zz = 0; zz < 8; ++zz) {
    size_t idx = (((size_t)nk)*256 + zb*8 + zz)*256 + x;
    x1pre[idx] += acc[zz]*sc;
  }
}

// ---------------- final: inorm(x1pre) + w0conv(v) -> fc1 -> sin -> fc2 ------
__global__ __launch_bounds__(256) void k_final(const float* __restrict__ x,
    const float* __restrict__ x1pre, const float2* __restrict__ stats2,
    const float* __restrict__ fc0w, const float* __restrict__ fc0b,
    const float* __restrict__ w0w, const float* __restrict__ w0b,
    const float* __restrict__ fc1w, const float* __restrict__ fc1b,
    const float* __restrict__ fc2w, const float* __restrict__ fc2b,
    float* __restrict__ out) {
  __shared__ float s_fc1w[2048], s_fc1b[128], s_fc2w[384], s_w0w[256], s_w0b[16], s_fc2b[3];
  int tid = threadIdx.x;
  for (int e = 0; e < 8; ++e) s_fc1w[tid + 256*e] = fc1w[tid + 256*e];
  if (tid < 128) s_fc1b[tid] = fc1b[tid];
  for (int e = 0; e < 2; ++e) { int q = tid + 256*e; if (q < 384) s_fc2w[q] = fc2w[q]; }
  s_w0w[tid] = w0w[tid];
  if (tid < 16) s_w0b[tid] = w0b[tid];
  if (tid < 3)  s_fc2b[tid] = fc2b[tid];
  __syncthreads();

  int bid = blockIdx.x;               // b*256 + h
  int hh = bid & 255, b = bid >> 8;
  int ww = tid;
  size_t pix = (size_t)hh*256 + ww;
  float xc0 = x[((size_t)b*3 + 0)*NPIX + pix];
  float xc1 = x[((size_t)b*3 + 1)*NPIX + pix];
  float xc2 = x[((size_t)b*3 + 2)*NPIX + pix];
  float gx = hh*(1.0f/255.0f), gy = ww*(1.0f/255.0f);
  float v[16], x1n[16], uo[16];
  #pragma unroll
  for (int k = 0; k < 16; ++k)
    v[k] = fc0b[k] + xc0*fc0w[k] + xc1*fc0w[16+k] + xc2*fc0w[32+k] + gx*fc0w[48+k] + gy*fc0w[64+k];
  #pragma unroll
  for (int k = 0; k < 16; ++k) {
    float2 st = stats2[b*16 + k];
    float xv = x1pre[((size_t)(b*16 + k))*NPIX + pix];
    x1n[k] = (xv - st.x)*st.y;
  }
  #pragma unroll
  for (int o = 0; o < 16; ++o) {
    float acc = s_w0b[o];
    #pragma unroll
    for (int k = 0; k < 16; ++k) acc = fmaf(v[k], s_w0w[o*16+k], acc);
    uo[o] = acc + x1n[o];
  }
  float o0 = 0.f, o1 = 0.f, o2 = 0.f;
  for (int jj = 0; jj < 128; ++jj) {
    float t = s_fc1b[jj];
    #pragma unroll
    for (int k = 0; k < 16; ++k) t = fmaf(uo[k], s_fc1w[k*128 + jj], t);
    float s = __sinf(t);
    o0 = fmaf(s, s_fc2w[jj*3+0], o0);
    o1 = fmaf(s, s_fc2w[jj*3+1], o1);
    o2 = fmaf(s, s_fc2w[jj*3+2], o2);
  }
  out[((size_t)b*3 + 0)*NPIX + pix] = o0 + s_fc2b[0];
  out[((size_t)b*3 + 1)*NPIX + pix] = o1 + s_fc2b[1];
  out[((size_t)b*3 + 2)*NPIX + pix] = o2 + s_fc2b[2];
}

// ---------------------------------------------------------------------------
extern "C" void kernel_launch(void* const* d_in, const int* in_sizes, int n_in,
                              void* d_out, int out_size, void* d_ws, size_t ws_size,
                              hipStream_t stream) {
  const float*  x    = (const float*)d_in[0];
  const float*  fc0w = (const float*)d_in[1];
  const float*  fc0b = (const float*)d_in[2];
  const float2* p1   = (const float2*)d_in[3];
  const float2* p2   = (const float2*)d_in[4];
  const float2* res  = (const float2*)d_in[5];
  const float*  w0w  = (const float*)d_in[6];
  const float*  w0b  = (const float*)d_in[7];
  const float*  fc1w = (const float*)d_in[8];
  const float*  fc1b = (const float*)d_in[9];
  const float*  fc2w = (const float*)d_in[10];
  const float*  fc2b = (const float*)d_in[11];
  const float*  txv  = (const float*)d_in[12];
  const float*  tyv  = (const float*)d_in[13];
  float* out = (float*)d_out;

  // workspace layout (bytes); NEED == proven-safe 252,774,400
  const size_t OFF_A1   = 0;            // 4 MiB
  const size_t OFF_A2T  = 4194304;      // 4 MiB
  const size_t OFF_E1   = 8388608;      // 4 MiB
  const size_t OFF_E2   = 12582912;     // 4 MiB
  const size_t OFF_ST1  = 16777216;
  const size_t OFF_ST2  = 16778240;
  const size_t OFF_OUT2 = 16779264;     // 64 KiB
  const size_t OFF_MT   = 16844800;     // 1 MiB
  const size_t OFF_S    = 17893376;     // 32 MiB  (S; later x1pre_wh real)
  const size_t OFF_X1   = 51447808;     // 32 MiB  (x1pre_hw real)
  const size_t OFF_A    = 85002240;     // 64 MiB  (F ping; later out1)
  const size_t OFF_B    = 152111104;    // 64 MiB  (F pong; alpha)
  const size_t OFF_G    = 219219968;    // 32 MiB  (G quarter; later U)
  const size_t NEED     = 252774400;
  if (ws_size < NEED) return;
  char* ws = (char*)d_ws;
  float2* A1  = (float2*)(ws + OFF_A1);
  float2* A2T = (float2*)(ws + OFF_A2T);
  float2* E1  = (float2*)(ws + OFF_E1);
  float2* E2  = (float2*)(ws + OFF_E2);
  float2* st1 = (float2*)(ws + OFF_ST1);
  float2* st2 = (float2*)(ws + OFF_ST2);
  float2* o2b = (float2*)(ws + OFF_OUT2);
  float2* Mt  = (float2*)(ws + OFF_MT);
  float2* Sb  = (float2*)(ws + OFF_S);
  float*  X1  = (float*)(ws + OFF_X1);
  float2* Ab  = (float2*)(ws + OFF_A);
  float2* Bb  = (float2*)(ws + OFF_B);
  float2* Gb  = (float2*)(ws + OFF_G);
  float2* Ub  = (float2*)(ws + OFF_G);   // reuse: G dead before k_U

  k_setup  <<<2048, 256, 0, stream>>>(p1, p2, txv, tyv, A1, A2T, E1, E2);
  k_stats_v<<<128, 256, 0, stream>>>(x, fc0w, fc0b, st1);
  // forward fft2: v -> alpha (in Bb)
  k_fft_v  <<<8192, 256, 0, stream>>>(x, fc0w, fc0b, st1, Ab);
  k_trans_c<<<dim3(64,128), 256, 0, stream>>>(Ab, Bb);
  k_fft_c  <<<8192, 256, 0, stream>>>(Bb, Ab, -1.f, 1.f);
  k_trans_c<<<dim3(64,128), 256, 0, stream>>>(Ab, Bb);          // Bb = alpha [b,i,o,x]
  // pole-residue spectral sums
  k_S      <<<2048, 256, 0, stream>>>(Bb, A2T, Sb);
  k_Mt     <<<2048, 64, 0, stream>>>(Sb, A1, Mt);
  k_out2   <<<32, 256, 0, stream>>>(Mt, res, o2b);
  // out1 = sum_i alpha*G, G computed in 4 i-quarters (fits 32 MiB region)
  for (int pass = 0; pass < 4; ++pass) {
    k_Gq      <<<512, 256, 0, stream>>>(res, A1, A2T, Gb, pass);
    k_out1_acc<<<1024, 256, 0, stream>>>(Bb, Gb, Ab, pass);     // Ab = out1
  }
  // inverse fft2 of out1 -> x1pre (real)
  k_fft_c  <<<8192, 256, 0, stream>>>(Ab, Bb, +1.f, 1.f);       // ifft over x
  k_trans_c<<<dim3(64,128), 256, 0, stream>>>(Bb, Ab);
  k_ifft_real<<<8192, 256, 0, stream>>>(Ab, (float*)Sb, 1.0f/65536.0f); // [img][w][h]
  k_trans_r<<<dim3(64,128), 256, 0, stream>>>((const float*)Sb, X1);    // [img][h][w]
  // transient part added into x1pre
  k_U      <<<2048, 256, 0, stream>>>(o2b, E1, Ub);
  k_x2t    <<<4096, 256, 0, stream>>>(Ub, E2, X1);
  // second instance norm + heads
  k_stats_p<<<128, 256, 0, stream>>>(X1, st2);
  k_final  <<<2048, 256, 0, stream>>>(x, X1, st2, fc0w, fc0b,
                                      w0w, w0b, fc1w, fc1b, fc2w, fc2b, out);
}